// Round 1
// baseline (582.721 us; speedup 1.0000x reference)
//
#include <hip/hip_runtime.h>

#define DIMN 2048
#define NH 16
#define HDN 128
#define SEQ 2048
#define BATCH 2
#define MROWS (BATCH * SEQ)  // 4096

typedef unsigned short u16;
using short8 = __attribute__((ext_vector_type(8))) short;
using f32x4 = __attribute__((ext_vector_type(4))) float;

__device__ __forceinline__ u16 f2bf(float f) {
  unsigned int x = __float_as_uint(f);
  unsigned int r = (x + 0x7fffu + ((x >> 16) & 1u)) >> 16;
  return (u16)r;
}
__device__ __forceinline__ float bf2f(u16 u) {
  return __uint_as_float(((unsigned int)u) << 16);
}

typedef const __attribute__((address_space(1))) void* gptr_t;
typedef __attribute__((address_space(3))) void* lptr_t;
__device__ __forceinline__ void gld16(const void* g, void* l) {
  __builtin_amdgcn_global_load_lds((gptr_t)g, (lptr_t)l, 16, 0, 0);
}

// ---------------- f32 -> bf16 convert ----------------
__global__ void k_f32_to_bf16(const float* __restrict__ src, u16* __restrict__ dst, int n) {
  int i = (blockIdx.x * blockDim.x + threadIdx.x) * 4;
  if (i + 3 >= n + 1) { }  // sizes are exact multiples of 1024; guard below anyway
  if (i + 3 < n) {
    float4 v = *(const float4*)(src + i);
    ushort4 o;
    o.x = f2bf(v.x); o.y = f2bf(v.y); o.z = f2bf(v.z); o.w = f2bf(v.w);
    *(ushort4*)(dst + i) = o;
  }
}

// ---------------- GEMM: C[m][n] = sum_k A[m][k]*Bt[n][k] + bias[n] ----------------
// m97 structure: 128x128 tile, BK=32, 4 waves (2x2), 4x4 16x16x32 MFMA frags/wave,
// global_load_lds width-16 staging, linear LDS.
template <int OUT_BF16>
__global__ __launch_bounds__(256) void k_gemm_bt(const u16* __restrict__ A,
                                                 const u16* __restrict__ Bt,
                                                 const float* __restrict__ bias,
                                                 void* __restrict__ Cout,
                                                 int M, int N, int K) {
  __shared__ u16 As[128][32];
  __shared__ u16 Bs[128][32];
  const int tid = threadIdx.x;
  const int lane = tid & 63;
  const int w = tid >> 6;
  const int wm = w >> 1, wn = w & 1;
  const int m0 = blockIdx.y * 128, n0 = blockIdx.x * 128;

  const int lrow = lane >> 2, lchunk = lane & 3;
  const u16* gA = A + (size_t)(m0 + w * 32 + lrow) * K + lchunk * 8;
  const u16* gB = Bt + (size_t)(n0 + w * 32 + lrow) * K + lchunk * 8;
  u16* lA = &As[w * 32][0];
  u16* lB = &Bs[w * 32][0];

  f32x4 acc[4][4] = {};

  for (int k0 = 0; k0 < K; k0 += 32) {
    __syncthreads();
    gld16(gA + k0, lA);
    gld16(gA + (size_t)16 * K + k0, lA + 16 * 32);
    gld16(gB + k0, lB);
    gld16(gB + (size_t)16 * K + k0, lB + 16 * 32);
    __syncthreads();

    short8 af[4], bfr[4];
#pragma unroll
    for (int i = 0; i < 4; ++i)
      af[i] = *(const short8*)&As[wm * 64 + i * 16 + (lane & 15)][(lane >> 4) * 8];
#pragma unroll
    for (int i = 0; i < 4; ++i)
      bfr[i] = *(const short8*)&Bs[wn * 64 + i * 16 + (lane & 15)][(lane >> 4) * 8];
#pragma unroll
    for (int i = 0; i < 4; ++i)
#pragma unroll
      for (int j = 0; j < 4; ++j)
        acc[i][j] = __builtin_amdgcn_mfma_f32_16x16x32_bf16(af[i], bfr[j], acc[i][j], 0, 0, 0);
  }

  const int rb = (lane >> 4) * 4, cb = lane & 15;
#pragma unroll
  for (int j = 0; j < 4; ++j) {
    const int col = n0 + wn * 64 + j * 16 + cb;
    const float bv = bias[col];
#pragma unroll
    for (int i = 0; i < 4; ++i) {
#pragma unroll
      for (int r = 0; r < 4; ++r) {
        const size_t row = (size_t)(m0 + wm * 64 + i * 16 + rb + r);
        float v = acc[i][j][r] + bv;
        if (OUT_BF16)
          ((u16*)Cout)[row * N + col] = f2bf(v);
        else
          ((float*)Cout)[row * N + col] = v;
      }
    }
  }
}

// ---------------- RoPE: Pin [M][DIM] bf16 -> Out [B*H][S][HD] bf16 ----------------
// cos[s][d] == cos[s][d+64] (emb = concat(freqs,freqs)), so one table read serves the pair.
__global__ void k_rope(const u16* __restrict__ Pin, const float* __restrict__ cosT,
                       const float* __restrict__ sinT, u16* __restrict__ Out) {
  int idx = blockIdx.x * blockDim.x + threadIdx.x;  // ((b*SEQ+s)*NH+h)*16 + d4
  int d4 = idx & 15;
  int h = (idx >> 4) & (NH - 1);
  int s = (idx >> 8) & (SEQ - 1);
  int b = idx >> 19;
  if (b >= BATCH) return;

  const u16* p1 = Pin + (size_t)(b * SEQ + s) * DIMN + h * HDN + d4 * 4;
  ushort4 u1 = *(const ushort4*)p1;
  ushort4 u2 = *(const ushort4*)(p1 + 64);
  float4 c = *(const float4*)(cosT + s * HDN + d4 * 4);
  float4 sn = *(const float4*)(sinT + s * HDN + d4 * 4);

  float a0 = bf2f(u1.x), a1 = bf2f(u1.y), a2 = bf2f(u1.z), a3 = bf2f(u1.w);
  float b0 = bf2f(u2.x), b1 = bf2f(u2.y), b2 = bf2f(u2.z), b3 = bf2f(u2.w);
  ushort4 o1, o2;
  o1.x = f2bf(a0 * c.x - b0 * sn.x);
  o1.y = f2bf(a1 * c.y - b1 * sn.y);
  o1.z = f2bf(a2 * c.z - b2 * sn.z);
  o1.w = f2bf(a3 * c.w - b3 * sn.w);
  o2.x = f2bf(b0 * c.x + a0 * sn.x);
  o2.y = f2bf(b1 * c.y + a1 * sn.y);
  o2.z = f2bf(b2 * c.z + a2 * sn.z);
  o2.w = f2bf(b3 * c.w + a3 * sn.w);

  u16* q = Out + ((size_t)(b * NH + h) * SEQ + s) * HDN + d4 * 4;
  *(ushort4*)q = o1;
  *(ushort4*)(q + 64) = o2;
}

// ---------------- V transpose: Vp [M][DIM] -> Vt [B*H][HD][S] ----------------
__global__ __launch_bounds__(256) void k_transpose_v(const u16* __restrict__ Vp,
                                                     u16* __restrict__ Vt) {
  __shared__ u16 tile[64][72];
  const int bh = blockIdx.z;
  const int b = bh >> 4, h = bh & 15;
  const int s0 = blockIdx.x * 64;
  const int d0 = blockIdx.y * 64;
  const int t = threadIdx.x;
#pragma unroll
  for (int i = 0; i < 4; ++i) {
    int lin = t + i * 256;
    int r = lin >> 4;
    int c = (lin & 15) * 4;
    ushort4 v = *(const ushort4*)(Vp + (size_t)(b * SEQ + s0 + r) * DIMN + h * HDN + d0 + c);
    *(ushort4*)&tile[r][c] = v;
  }
  __syncthreads();
#pragma unroll
  for (int i = 0; i < 4; ++i) {
    int lin = t + i * 256;
    int d = lin >> 4;
    int s4 = (lin & 15) * 4;
    ushort4 o;
    o.x = tile[s4 + 0][d];
    o.y = tile[s4 + 1][d];
    o.z = tile[s4 + 2][d];
    o.w = tile[s4 + 3][d];
    *(ushort4*)(Vt + ((size_t)bh * HDN + d0 + d) * SEQ + s0 + s4) = o;
  }
}

// ---------------- Flash attention (causal) ----------------
// grid: (SEQ/64, B*H); 4 waves, each owns 16 q-rows. KVBLK=32.
// Qh,Kh: [B*H][S][HD] bf16 (rope'd); Vt: [B*H][HD][S] bf16; AO: [M][DIM] bf16.
__global__ __launch_bounds__(256) void k_attn(const u16* __restrict__ Qh,
                                              const u16* __restrict__ Kh,
                                              const u16* __restrict__ Vt,
                                              u16* __restrict__ AO) {
  __shared__ u16 Ks[32][128];
  __shared__ u16 Vs[128][32];
  __shared__ u16 Ps[4][16][32];
  const int tid = threadIdx.x, lane = tid & 63, w = tid >> 6;
  const int bh = blockIdx.y;
  const int b = bh >> 4, h = bh & 15;
  const int q0 = blockIdx.x * 64;
  const int qw = q0 + w * 16;
  const int rb = (lane >> 4) * 4, cb = lane & 15;
  const int lrow = lane >> 2, lchunk = lane & 3;

  // hoist Q A-fragments into registers (row = lane&15, k = (lane>>4)*8 + ks*32)
  short8 aq[4];
  {
    const u16* qp = Qh + ((size_t)bh * SEQ + qw + cb) * HDN + (lane >> 4) * 8;
#pragma unroll
    for (int ks = 0; ks < 4; ++ks) aq[ks] = *(const short8*)(qp + ks * 32);
  }

  f32x4 accO[8] = {};
  float m_i[4], l_i[4];
#pragma unroll
  for (int r = 0; r < 4; ++r) {
    m_i[r] = -1e30f;
    l_i[r] = 0.f;
  }
  const float scale = 0.08838834764831843f;  // 1/sqrt(128)

  const u16* gK = Kh + (size_t)bh * SEQ * HDN;
  const u16* gV = Vt + (size_t)bh * HDN * SEQ;

  const int nkv = q0 / 32 + 2;
  for (int t = 0; t < nkv; ++t) {
    const int kv0 = t * 32;
    __syncthreads();
    // stage K tile [32][128] (contiguous 8KB)
    {
      const u16* src = gK + (size_t)kv0 * HDN + w * 1024 + lane * 8;
      u16* dst = &Ks[0][0] + w * 1024;
      gld16(src, dst);
      gld16(src + 512, dst + 512);
    }
    // stage Vt tile [128][32]
#pragma unroll
    for (int j = 0; j < 2; ++j) {
      const int row = w * 32 + j * 16;
      gld16(gV + (size_t)(row + lrow) * SEQ + kv0 + lchunk * 8, &Vs[row][0]);
    }
    __syncthreads();

    // S = Q K^T  (rows q, cols kv)
    f32x4 sc[2] = {};
#pragma unroll
    for (int f = 0; f < 2; ++f)
#pragma unroll
      for (int ks = 0; ks < 4; ++ks) {
        short8 bk = *(const short8*)&Ks[f * 16 + cb][ks * 32 + (lane >> 4) * 8];
        sc[f] = __builtin_amdgcn_mfma_f32_16x16x32_bf16(aq[ks], bk, sc[f], 0, 0, 0);
      }

    // scale + causal mask
#pragma unroll
    for (int f = 0; f < 2; ++f) {
      const int kva = kv0 + f * 16 + cb;
#pragma unroll
      for (int r = 0; r < 4; ++r) {
        float v = sc[f][r] * scale;
        sc[f][r] = (kva <= qw + rb + r) ? v : -1e30f;
      }
    }

    // online softmax (row stats across 16-lane group)
    float pm[4];
#pragma unroll
    for (int r = 0; r < 4; ++r) {
      float v = fmaxf(sc[0][r], sc[1][r]);
      v = fmaxf(v, __shfl_xor(v, 1));
      v = fmaxf(v, __shfl_xor(v, 2));
      v = fmaxf(v, __shfl_xor(v, 4));
      v = fmaxf(v, __shfl_xor(v, 8));
      pm[r] = v;
    }
    float alpha[4];
#pragma unroll
    for (int r = 0; r < 4; ++r) {
      float nm = fmaxf(m_i[r], pm[r]);
      alpha[r] = __expf(m_i[r] - nm);
      m_i[r] = nm;
    }
#pragma unroll
    for (int f = 0; f < 2; ++f)
#pragma unroll
      for (int r = 0; r < 4; ++r) sc[f][r] = __expf(sc[f][r] - m_i[r]);
#pragma unroll
    for (int r = 0; r < 4; ++r) {
      float s = sc[0][r] + sc[1][r];
      s += __shfl_xor(s, 1);
      s += __shfl_xor(s, 2);
      s += __shfl_xor(s, 4);
      s += __shfl_xor(s, 8);
      l_i[r] = l_i[r] * alpha[r] + s;
    }
#pragma unroll
    for (int nf = 0; nf < 8; ++nf)
#pragma unroll
      for (int r = 0; r < 4; ++r) accO[nf][r] *= alpha[r];

    // P -> LDS (D-layout) then re-read as A-fragments
#pragma unroll
    for (int f = 0; f < 2; ++f)
#pragma unroll
      for (int r = 0; r < 4; ++r) Ps[w][rb + r][f * 16 + cb] = f2bf(sc[f][r]);
    __syncthreads();
    short8 pa = *(const short8*)&Ps[w][cb][(lane >> 4) * 8];
#pragma unroll
    for (int nf = 0; nf < 8; ++nf) {
      short8 bv = *(const short8*)&Vs[nf * 16 + cb][(lane >> 4) * 8];
      accO[nf] = __builtin_amdgcn_mfma_f32_16x16x32_bf16(pa, bv, accO[nf], 0, 0, 0);
    }
  }

  // epilogue: O / l_i -> AO[b*S+q][h*128 + d]
  float inv[4];
#pragma unroll
  for (int r = 0; r < 4; ++r) inv[r] = 1.f / l_i[r];
#pragma unroll
  for (int nf = 0; nf < 8; ++nf)
#pragma unroll
    for (int r = 0; r < 4; ++r) {
      const size_t row = (size_t)(b * SEQ + qw + rb + r);
      AO[row * DIMN + h * HDN + nf * 16 + cb] = f2bf(accO[nf][r] * inv[r]);
    }
}

// ---------------- launch ----------------
extern "C" void kernel_launch(void* const* d_in, const int* in_sizes, int n_in,
                              void* d_out, int out_size, void* d_ws, size_t ws_size,
                              hipStream_t stream) {
  const float* query = (const float*)d_in[0];
  const float* key_value = (const float*)d_in[1];
  const float* cosT = (const float*)d_in[2];
  const float* sinT = (const float*)d_in[3];
  const float* wq = (const float*)d_in[4];
  const float* bq = (const float*)d_in[5];
  const float* wk = (const float*)d_in[6];
  const float* bk = (const float*)d_in[7];
  const float* wv = (const float*)d_in[8];
  const float* bv = (const float*)d_in[9];
  const float* wo = (const float*)d_in[10];
  const float* bo = (const float*)d_in[11];
  float* out = (float*)d_out;

  const size_t WB = (size_t)DIMN * DIMN * 2;   // weight bf16 bytes
  const size_t XB = (size_t)MROWS * DIMN * 2;  // activation bf16 bytes
  char* ws = (char*)d_ws;
  size_t off = 0;
  auto alloc = [&](size_t bytes) {
    char* p = ws + off;
    off += bytes;
    return p;
  };
  u16* wq_bf = (u16*)alloc(WB);
  u16* wk_bf = (u16*)alloc(WB);
  u16* wv_bf = (u16*)alloc(WB);
  u16* wo_bf = (u16*)alloc(WB);
  u16* xq_bf = (u16*)alloc(XB);
  u16* xkv_bf = (u16*)alloc(XB);
  u16* Qp = (u16*)alloc(XB);
  u16* Kp = (u16*)alloc(XB);
  u16* Vp = (u16*)alloc(XB);
  u16* Qh = (u16*)alloc(XB);
  u16* Kh = (u16*)alloc(XB);
  u16* Vt = (u16*)alloc(XB);
  u16* AO = (u16*)alloc(XB);

  auto conv = [&](const float* s, u16* d, int n) {
    k_f32_to_bf16<<<dim3(n / 4 / 256), dim3(256), 0, stream>>>(s, d, n);
  };
  conv(wq, wq_bf, DIMN * DIMN);
  conv(wk, wk_bf, DIMN * DIMN);
  conv(wv, wv_bf, DIMN * DIMN);
  conv(wo, wo_bf, DIMN * DIMN);
  conv(query, xq_bf, MROWS * DIMN);
  conv(key_value, xkv_bf, MROWS * DIMN);

  dim3 gg(DIMN / 128, MROWS / 128);
  k_gemm_bt<1><<<gg, 256, 0, stream>>>(xq_bf, wq_bf, bq, Qp, MROWS, DIMN, DIMN);
  k_gemm_bt<1><<<gg, 256, 0, stream>>>(xkv_bf, wk_bf, bk, Kp, MROWS, DIMN, DIMN);
  k_gemm_bt<1><<<gg, 256, 0, stream>>>(xkv_bf, wv_bf, bv, Vp, MROWS, DIMN, DIMN);

  const int ropeN = BATCH * SEQ * NH * 16;
  k_rope<<<dim3(ropeN / 256), dim3(256), 0, stream>>>(Qp, cosT, sinT, Qh);
  k_rope<<<dim3(ropeN / 256), dim3(256), 0, stream>>>(Kp, cosT, sinT, Kh);
  k_transpose_v<<<dim3(SEQ / 64, 2, BATCH * NH), dim3(256), 0, stream>>>(Vp, Vt);

  k_attn<<<dim3(SEQ / 64, BATCH * NH), dim3(256), 0, stream>>>(Qh, Kh, Vt, AO);

  k_gemm_bt<0><<<gg, 256, 0, stream>>>(AO, wo_bf, bo, out, MROWS, DIMN, DIMN);
}

// Round 2
// 410.041 us; speedup vs baseline: 1.4211x; 1.4211x over previous
//
#include <hip/hip_runtime.h>

#define DIMN 2048
#define NH 16
#define HDN 128
#define SEQ 2048
#define BATCH 2
#define MROWS (BATCH * SEQ)  // 4096

typedef unsigned short u16;
using short8 = __attribute__((ext_vector_type(8))) short;
using f32x4 = __attribute__((ext_vector_type(4))) float;

__device__ __forceinline__ u16 f2bf(float f) {
  unsigned int x = __float_as_uint(f);
  unsigned int r = (x + 0x7fffu + ((x >> 16) & 1u)) >> 16;
  return (u16)r;
}
__device__ __forceinline__ float bf2f(u16 u) {
  return __uint_as_float(((unsigned int)u) << 16);
}

typedef const __attribute__((address_space(1))) void* gptr_t;
typedef __attribute__((address_space(3))) void* lptr_t;
__device__ __forceinline__ void gld16(const void* g, void* l) {
  __builtin_amdgcn_global_load_lds((gptr_t)g, (lptr_t)l, 16, 0, 0);
}

// ---------------- f32 -> bf16 convert ----------------
__global__ void k_f32_to_bf16(const float* __restrict__ src, u16* __restrict__ dst, int n) {
  int i = (blockIdx.x * blockDim.x + threadIdx.x) * 4;
  if (i + 3 < n) {
    float4 v = *(const float4*)(src + i);
    ushort4 o;
    o.x = f2bf(v.x); o.y = f2bf(v.y); o.z = f2bf(v.z); o.w = f2bf(v.w);
    *(ushort4*)(dst + i) = o;
  }
}

// ---------------- GEMM: C[m][n] = sum_k A[m][k]*Bt[n][k] + bias[n] ----------------
template <int OUT_BF16>
__global__ __launch_bounds__(256) void k_gemm_bt(const u16* __restrict__ A,
                                                 const u16* __restrict__ Bt,
                                                 const float* __restrict__ bias,
                                                 void* __restrict__ Cout,
                                                 int M, int N, int K) {
  __shared__ u16 As[128][32];
  __shared__ u16 Bs[128][32];
  const int tid = threadIdx.x;
  const int lane = tid & 63;
  const int w = tid >> 6;
  const int wm = w >> 1, wn = w & 1;
  const int m0 = blockIdx.y * 128, n0 = blockIdx.x * 128;

  const int lrow = lane >> 2, lchunk = lane & 3;
  const u16* gA = A + (size_t)(m0 + w * 32 + lrow) * K + lchunk * 8;
  const u16* gB = Bt + (size_t)(n0 + w * 32 + lrow) * K + lchunk * 8;
  u16* lA = &As[w * 32][0];
  u16* lB = &Bs[w * 32][0];

  f32x4 acc[4][4] = {};

  for (int k0 = 0; k0 < K; k0 += 32) {
    __syncthreads();
    gld16(gA + k0, lA);
    gld16(gA + (size_t)16 * K + k0, lA + 16 * 32);
    gld16(gB + k0, lB);
    gld16(gB + (size_t)16 * K + k0, lB + 16 * 32);
    __syncthreads();

    short8 af[4], bfr[4];
#pragma unroll
    for (int i = 0; i < 4; ++i)
      af[i] = *(const short8*)&As[wm * 64 + i * 16 + (lane & 15)][(lane >> 4) * 8];
#pragma unroll
    for (int i = 0; i < 4; ++i)
      bfr[i] = *(const short8*)&Bs[wn * 64 + i * 16 + (lane & 15)][(lane >> 4) * 8];
#pragma unroll
    for (int i = 0; i < 4; ++i)
#pragma unroll
      for (int j = 0; j < 4; ++j)
        acc[i][j] = __builtin_amdgcn_mfma_f32_16x16x32_bf16(af[i], bfr[j], acc[i][j], 0, 0, 0);
  }

  const int rb = (lane >> 4) * 4, cb = lane & 15;
#pragma unroll
  for (int j = 0; j < 4; ++j) {
    const int col = n0 + wn * 64 + j * 16 + cb;
    const float bv = bias[col];
#pragma unroll
    for (int i = 0; i < 4; ++i) {
#pragma unroll
      for (int r = 0; r < 4; ++r) {
        const size_t row = (size_t)(m0 + wm * 64 + i * 16 + rb + r);
        float v = acc[i][j][r] + bv;
        if (OUT_BF16)
          ((u16*)Cout)[row * N + col] = f2bf(v);
        else
          ((float*)Cout)[row * N + col] = v;
      }
    }
  }
}

// ---------------- RoPE: Pin [M][DIM] bf16 -> Out [B*H][S][HD] bf16 ----------------
__global__ void k_rope(const u16* __restrict__ Pin, const float* __restrict__ cosT,
                       const float* __restrict__ sinT, u16* __restrict__ Out) {
  int idx = blockIdx.x * blockDim.x + threadIdx.x;  // ((b*SEQ+s)*NH+h)*16 + d4
  int d4 = idx & 15;
  int h = (idx >> 4) & (NH - 1);
  int s = (idx >> 8) & (SEQ - 1);
  int b = idx >> 19;
  if (b >= BATCH) return;

  const u16* p1 = Pin + (size_t)(b * SEQ + s) * DIMN + h * HDN + d4 * 4;
  ushort4 u1 = *(const ushort4*)p1;
  ushort4 u2 = *(const ushort4*)(p1 + 64);
  float4 c = *(const float4*)(cosT + s * HDN + d4 * 4);
  float4 sn = *(const float4*)(sinT + s * HDN + d4 * 4);

  float a0 = bf2f(u1.x), a1 = bf2f(u1.y), a2 = bf2f(u1.z), a3 = bf2f(u1.w);
  float b0 = bf2f(u2.x), b1 = bf2f(u2.y), b2 = bf2f(u2.z), b3 = bf2f(u2.w);
  ushort4 o1, o2;
  o1.x = f2bf(a0 * c.x - b0 * sn.x);
  o1.y = f2bf(a1 * c.y - b1 * sn.y);
  o1.z = f2bf(a2 * c.z - b2 * sn.z);
  o1.w = f2bf(a3 * c.w - b3 * sn.w);
  o2.x = f2bf(b0 * c.x + a0 * sn.x);
  o2.y = f2bf(b1 * c.y + a1 * sn.y);
  o2.z = f2bf(b2 * c.z + a2 * sn.z);
  o2.w = f2bf(b3 * c.w + a3 * sn.w);

  u16* q = Out + ((size_t)(b * NH + h) * SEQ + s) * HDN + d4 * 4;
  *(ushort4*)q = o1;
  *(ushort4*)(q + 64) = o2;
}

// ---------------- V transpose: Vp [M][DIM] -> Vt [B*H][HD][S] ----------------
__global__ __launch_bounds__(256) void k_transpose_v(const u16* __restrict__ Vp,
                                                     u16* __restrict__ Vt) {
  __shared__ u16 tile[64][72];
  const int bh = blockIdx.z;
  const int b = bh >> 4, h = bh & 15;
  const int s0 = blockIdx.x * 64;
  const int d0 = blockIdx.y * 64;
  const int t = threadIdx.x;
#pragma unroll
  for (int i = 0; i < 4; ++i) {
    int lin = t + i * 256;
    int r = lin >> 4;
    int c = (lin & 15) * 4;
    ushort4 v = *(const ushort4*)(Vp + (size_t)(b * SEQ + s0 + r) * DIMN + h * HDN + d0 + c);
    *(ushort4*)&tile[r][c] = v;
  }
  __syncthreads();
#pragma unroll
  for (int i = 0; i < 4; ++i) {
    int lin = t + i * 256;
    int d = lin >> 4;
    int s4 = (lin & 15) * 4;
    ushort4 o;
    o.x = tile[s4 + 0][d];
    o.y = tile[s4 + 1][d];
    o.z = tile[s4 + 2][d];
    o.w = tile[s4 + 3][d];
    *(ushort4*)(Vt + ((size_t)bh * HDN + d0 + d) * SEQ + s0 + s4) = o;
  }
}

// ---------------- Flash attention (causal), v2 ----------------
// grid: (SEQ/128, B*H); 4 waves x 32 q-rows; KVBLK=64.
// K tile [64][128] and V tile [128][64] staged via global_load_lds with XOR
// chunk-swizzle applied on the GLOBAL source (LDS dest stays linear); reads
// apply the same swizzle. P bounced through a padded per-wave LDS buffer
// (no barrier needed: LDS ops are in-order per wave).
__global__ __launch_bounds__(256, 2) void k_attn(const u16* __restrict__ Qh,
                                                 const u16* __restrict__ Kh,
                                                 const u16* __restrict__ Vt,
                                                 u16* __restrict__ AO) {
  __shared__ u16 Ks[64 * 128];   // swizzled storage, row=kv (256B), 16 chunks/row
  __shared__ u16 Vs[128 * 64];   // swizzled storage, row=d (128B), 8 chunks/row
  __shared__ u16 Ps[4][32][72];  // per-wave P, +8 pad -> 144B stride
  const int tid = threadIdx.x, lane = tid & 63, w = tid >> 6;
  const int bh = blockIdx.y;
  const int b = bh >> 4, h = bh & 15;
  const int q0 = blockIdx.x * 128;
  const int qw = q0 + w * 32;
  const int rb = (lane >> 4) * 4, cb = lane & 15, kh = lane >> 4;
  const int sw = cb & 7;  // read-side chunk swizzle for this lane's rows

  // staging address precompute (linear LDS dest <- swizzled global src)
  int rK[4], cK[4], rV[4], cV[4];
#pragma unroll
  for (int i = 0; i < 4; ++i) {
    const int off = w * 4096 + i * 1024 + lane * 16;  // byte offset in 16KB tile
    rK[i] = off >> 8;
    cK[i] = ((off >> 4) & 15) ^ (rK[i] & 7);
    rV[i] = off >> 7;
    cV[i] = ((off >> 4) & 7) ^ (rV[i] & 7);
  }

  // hoist Q A-fragments: aq[rf][ks], row = qw + rf*16 + cb, k = ks*32 + kh*8
  short8 aq[2][4];
  {
    const u16* qp = Qh + ((size_t)bh * SEQ + qw + cb) * HDN + kh * 8;
#pragma unroll
    for (int rf = 0; rf < 2; ++rf)
#pragma unroll
      for (int ks = 0; ks < 4; ++ks) aq[rf][ks] = *(const short8*)(qp + rf * 16 * HDN + ks * 32);
  }

  f32x4 accO[2][8] = {};
  float m_i[2][4], l_i[2][4];
#pragma unroll
  for (int rf = 0; rf < 2; ++rf)
#pragma unroll
    for (int r = 0; r < 4; ++r) {
      m_i[rf][r] = -1e30f;
      l_i[rf][r] = 0.f;
    }
  const float scale = 0.08838834764831843f;  // 1/sqrt(128)

  const u16* gK = Kh + (size_t)bh * SEQ * HDN;
  const u16* gV = Vt + (size_t)bh * HDN * SEQ;

  const int nt = q0 / 64 + 2;
  for (int t = 0; t < nt; ++t) {
    const int kv0 = t * 64;
    __syncthreads();
#pragma unroll
    for (int i = 0; i < 4; ++i)
      gld16(gK + (size_t)(kv0 + rK[i]) * HDN + cK[i] * 8, Ks + w * 2048 + i * 512 + lane * 8);
#pragma unroll
    for (int i = 0; i < 4; ++i)
      gld16(gV + (size_t)rV[i] * SEQ + kv0 + cV[i] * 8, Vs + w * 2048 + i * 512 + lane * 8);
    __syncthreads();

    if (kv0 >= qw + 32) continue;  // fully masked for this wave (barriers already done)

    // S = Q K^T : sc[rf][f], rows qw+rf*16.., cols kv0+f*16..
    f32x4 sc[2][4] = {};
#pragma unroll
    for (int f = 0; f < 4; ++f)
#pragma unroll
      for (int ks = 0; ks < 4; ++ks) {
        const int krow = f * 16 + cb;
        short8 bk = *(const short8*)(Ks + krow * 128 + (((ks * 4 + kh) ^ sw) * 8));
#pragma unroll
        for (int rf = 0; rf < 2; ++rf)
          sc[rf][f] = __builtin_amdgcn_mfma_f32_16x16x32_bf16(aq[rf][ks], bk, sc[rf][f], 0, 0, 0);
      }

    // scale + causal mask (mask math only on tail tiles)
    const bool tail = (kv0 + 63 > qw);
    if (tail) {
#pragma unroll
      for (int rf = 0; rf < 2; ++rf)
#pragma unroll
        for (int f = 0; f < 4; ++f) {
          const int kva = kv0 + f * 16 + cb;
#pragma unroll
          for (int r = 0; r < 4; ++r) {
            float v = sc[rf][f][r] * scale;
            sc[rf][f][r] = (kva <= qw + rf * 16 + rb + r) ? v : -1e30f;
          }
        }
    } else {
#pragma unroll
      for (int rf = 0; rf < 2; ++rf)
#pragma unroll
        for (int f = 0; f < 4; ++f)
#pragma unroll
          for (int r = 0; r < 4; ++r) sc[rf][f][r] *= scale;
    }

    // online softmax per row (16-lane group reduce)
#pragma unroll
    for (int rf = 0; rf < 2; ++rf) {
      float pm[4], alpha[4];
#pragma unroll
      for (int r = 0; r < 4; ++r) {
        float v = fmaxf(fmaxf(sc[rf][0][r], sc[rf][1][r]), fmaxf(sc[rf][2][r], sc[rf][3][r]));
        v = fmaxf(v, __shfl_xor(v, 1));
        v = fmaxf(v, __shfl_xor(v, 2));
        v = fmaxf(v, __shfl_xor(v, 4));
        v = fmaxf(v, __shfl_xor(v, 8));
        pm[r] = v;
      }
#pragma unroll
      for (int r = 0; r < 4; ++r) {
        float nm = fmaxf(m_i[rf][r], pm[r]);
        alpha[r] = __expf(m_i[rf][r] - nm);
        m_i[rf][r] = nm;
      }
#pragma unroll
      for (int f = 0; f < 4; ++f)
#pragma unroll
        for (int r = 0; r < 4; ++r) sc[rf][f][r] = __expf(sc[rf][f][r] - m_i[rf][r]);
#pragma unroll
      for (int r = 0; r < 4; ++r) {
        float s = sc[rf][0][r] + sc[rf][1][r] + sc[rf][2][r] + sc[rf][3][r];
        s += __shfl_xor(s, 1);
        s += __shfl_xor(s, 2);
        s += __shfl_xor(s, 4);
        s += __shfl_xor(s, 8);
        l_i[rf][r] = l_i[rf][r] * alpha[r] + s;
      }
#pragma unroll
      for (int nf = 0; nf < 8; ++nf)
#pragma unroll
        for (int r = 0; r < 4; ++r) accO[rf][nf][r] *= alpha[r];
    }

    // P -> per-wave padded LDS (no barrier: intra-wave LDS is in-order)
    asm volatile("" ::: "memory");
#pragma unroll
    for (int rf = 0; rf < 2; ++rf)
#pragma unroll
      for (int f = 0; f < 4; ++f)
#pragma unroll
        for (int r = 0; r < 4; ++r)
          Ps[w][rf * 16 + rb + r][f * 16 + cb] = f2bf(sc[rf][f][r]);
    asm volatile("" ::: "memory");

    short8 pa[2][2];
#pragma unroll
    for (int rf = 0; rf < 2; ++rf)
#pragma unroll
      for (int kk = 0; kk < 2; ++kk)
        pa[rf][kk] = *(const short8*)&Ps[w][rf * 16 + cb][kk * 32 + kh * 8];

    // O += P V  (V tile rows = d, swizzled chunks)
#pragma unroll
    for (int nf = 0; nf < 8; ++nf)
#pragma unroll
      for (int kk = 0; kk < 2; ++kk) {
        const int vrow = nf * 16 + cb;
        short8 bv = *(const short8*)(Vs + vrow * 64 + (((kk * 4 + kh) ^ sw) * 8));
#pragma unroll
        for (int rf = 0; rf < 2; ++rf)
          accO[rf][nf] = __builtin_amdgcn_mfma_f32_16x16x32_bf16(pa[rf][kk], bv, accO[rf][nf], 0, 0, 0);
      }
  }

  // epilogue
#pragma unroll
  for (int rf = 0; rf < 2; ++rf) {
    float inv[4];
#pragma unroll
    for (int r = 0; r < 4; ++r) inv[r] = 1.f / l_i[rf][r];
#pragma unroll
    for (int nf = 0; nf < 8; ++nf)
#pragma unroll
      for (int r = 0; r < 4; ++r) {
        const size_t row = (size_t)(b * SEQ + qw + rf * 16 + rb + r);
        AO[row * DIMN + h * HDN + nf * 16 + cb] = f2bf(accO[rf][nf][r] * inv[r]);
      }
  }
}

// ---------------- launch ----------------
extern "C" void kernel_launch(void* const* d_in, const int* in_sizes, int n_in,
                              void* d_out, int out_size, void* d_ws, size_t ws_size,
                              hipStream_t stream) {
  const float* query = (const float*)d_in[0];
  const float* key_value = (const float*)d_in[1];
  const float* cosT = (const float*)d_in[2];
  const float* sinT = (const float*)d_in[3];
  const float* wq = (const float*)d_in[4];
  const float* bq = (const float*)d_in[5];
  const float* wk = (const float*)d_in[6];
  const float* bk = (const float*)d_in[7];
  const float* wv = (const float*)d_in[8];
  const float* bv = (const float*)d_in[9];
  const float* wo = (const float*)d_in[10];
  const float* bo = (const float*)d_in[11];
  float* out = (float*)d_out;

  const size_t WB = (size_t)DIMN * DIMN * 2;
  const size_t XB = (size_t)MROWS * DIMN * 2;
  char* ws = (char*)d_ws;
  size_t off = 0;
  auto alloc = [&](size_t bytes) {
    char* p = ws + off;
    off += bytes;
    return p;
  };
  u16* wq_bf = (u16*)alloc(WB);
  u16* wk_bf = (u16*)alloc(WB);
  u16* wv_bf = (u16*)alloc(WB);
  u16* wo_bf = (u16*)alloc(WB);
  u16* xq_bf = (u16*)alloc(XB);
  u16* xkv_bf = (u16*)alloc(XB);
  u16* Qp = (u16*)alloc(XB);
  u16* Kp = (u16*)alloc(XB);
  u16* Vp = (u16*)alloc(XB);
  u16* Qh = (u16*)alloc(XB);
  u16* Kh = (u16*)alloc(XB);
  u16* Vt = (u16*)alloc(XB);
  u16* AO = (u16*)alloc(XB);

  auto conv = [&](const float* s, u16* d, int n) {
    k_f32_to_bf16<<<dim3(n / 4 / 256), dim3(256), 0, stream>>>(s, d, n);
  };
  conv(wq, wq_bf, DIMN * DIMN);
  conv(wk, wk_bf, DIMN * DIMN);
  conv(wv, wv_bf, DIMN * DIMN);
  conv(wo, wo_bf, DIMN * DIMN);
  conv(query, xq_bf, MROWS * DIMN);
  conv(key_value, xkv_bf, MROWS * DIMN);

  dim3 gg(DIMN / 128, MROWS / 128);
  k_gemm_bt<1><<<gg, 256, 0, stream>>>(xq_bf, wq_bf, bq, Qp, MROWS, DIMN, DIMN);
  k_gemm_bt<1><<<gg, 256, 0, stream>>>(xkv_bf, wk_bf, bk, Kp, MROWS, DIMN, DIMN);
  k_gemm_bt<1><<<gg, 256, 0, stream>>>(xkv_bf, wv_bf, bv, Vp, MROWS, DIMN, DIMN);

  const int ropeN = BATCH * SEQ * NH * 16;
  k_rope<<<dim3(ropeN / 256), dim3(256), 0, stream>>>(Qp, cosT, sinT, Qh);
  k_rope<<<dim3(ropeN / 256), dim3(256), 0, stream>>>(Kp, cosT, sinT, Kh);
  k_transpose_v<<<dim3(SEQ / 64, 2, BATCH * NH), dim3(256), 0, stream>>>(Vp, Vt);

  k_attn<<<dim3(SEQ / 128, BATCH * NH), dim3(256), 0, stream>>>(Qh, Kh, Vt, AO);

  k_gemm_bt<0><<<gg, 256, 0, stream>>>(AO, wo_bf, bo, out, MROWS, DIMN, DIMN);
}

// Round 3
// 349.419 us; speedup vs baseline: 1.6677x; 1.1735x over previous
//
#include <hip/hip_runtime.h>

#define DIMN 2048
#define NH 16
#define HDN 128
#define SEQ 2048
#define BATCH 2
#define MROWS (BATCH * SEQ)  // 4096

typedef unsigned short u16;
using short8 = __attribute__((ext_vector_type(8))) short;
using f32x4 = __attribute__((ext_vector_type(4))) float;

__device__ __forceinline__ u16 f2bf(float f) {
  unsigned int x = __float_as_uint(f);
  unsigned int r = (x + 0x7fffu + ((x >> 16) & 1u)) >> 16;
  return (u16)r;
}
__device__ __forceinline__ float bf2f(u16 u) {
  return __uint_as_float(((unsigned int)u) << 16);
}

typedef const __attribute__((address_space(1))) void* gptr_t;
typedef __attribute__((address_space(3))) void* lptr_t;
__device__ __forceinline__ void gld16(const void* g, void* l) {
  __builtin_amdgcn_global_load_lds((gptr_t)g, (lptr_t)l, 16, 0, 0);
}
// drain this wave's outstanding global_load_lds, then block barrier
__device__ __forceinline__ void waitbar() {
  asm volatile("s_waitcnt vmcnt(0)" ::: "memory");
  __builtin_amdgcn_s_barrier();
  __builtin_amdgcn_sched_barrier(0);
}

// ---------------- f32 -> bf16 convert ----------------
__global__ void k_f32_to_bf16(const float* __restrict__ src, u16* __restrict__ dst, int n) {
  int i = (blockIdx.x * blockDim.x + threadIdx.x) * 4;
  if (i + 3 < n) {
    float4 v = *(const float4*)(src + i);
    ushort4 o;
    o.x = f2bf(v.x); o.y = f2bf(v.y); o.z = f2bf(v.z); o.w = f2bf(v.w);
    *(ushort4*)(dst + i) = o;
  }
}

// ---------------- GEMM: C[m][n] = sum_k A[m][k]*Bt[n][k] + bias[n] ----------------
// m97 structure + double-buffered 2-phase prefetch + bijective XCD swizzle.
template <int OUT_BF16>
__global__ __launch_bounds__(256) void k_gemm_bt(const u16* __restrict__ A,
                                                 const u16* __restrict__ Bt,
                                                 const float* __restrict__ bias,
                                                 void* __restrict__ Cout,
                                                 int M, int N, int K) {
  __shared__ u16 As[2][128][32];
  __shared__ u16 Bs[2][128][32];
  const int tid = threadIdx.x;
  const int lane = tid & 63;
  const int w = tid >> 6;
  const int wm = w >> 1, wn = w & 1;
  const int kh = lane >> 4;

  // XCD-aware bijective swizzle (nwg % 8 == 0 by construction)
  int id = blockIdx.y * gridDim.x + blockIdx.x;
  const int nwg = gridDim.x * gridDim.y;
  const int cpx = nwg >> 3;
  id = (id & 7) * cpx + (id >> 3);
  const int nbx = N / 128;
  const int n0 = (id % nbx) * 128;
  const int m0 = (id / nbx) * 128;

  const int lrow = lane >> 2, lchunk = lane & 3;
  const u16* gA = A + (size_t)(m0 + w * 32 + lrow) * K + lchunk * 8;
  const u16* gB = Bt + (size_t)(n0 + w * 32 + lrow) * K + lchunk * 8;

  auto stage = [&](int buf, int k0) {
    gld16(gA + k0, &As[buf][w * 32][0]);
    gld16(gA + (size_t)16 * K + k0, &As[buf][w * 32 + 16][0]);
    gld16(gB + k0, &Bs[buf][w * 32][0]);
    gld16(gB + (size_t)16 * K + k0, &Bs[buf][w * 32 + 16][0]);
  };

  f32x4 acc[4][4] = {};
  stage(0, 0);
  waitbar();
  int cur = 0;

  for (int k0 = 0; k0 < K; k0 += 32) {
    if (k0 + 32 < K) stage(cur ^ 1, k0 + 32);

    short8 af[4], bfr[4];
#pragma unroll
    for (int i = 0; i < 4; ++i)
      af[i] = *(const short8*)&As[cur][wm * 64 + i * 16 + (lane & 15)][kh * 8];
#pragma unroll
    for (int i = 0; i < 4; ++i)
      bfr[i] = *(const short8*)&Bs[cur][wn * 64 + i * 16 + (lane & 15)][kh * 8];
#pragma unroll
    for (int i = 0; i < 4; ++i)
#pragma unroll
      for (int j = 0; j < 4; ++j)
        acc[i][j] = __builtin_amdgcn_mfma_f32_16x16x32_bf16(af[i], bfr[j], acc[i][j], 0, 0, 0);

    waitbar();
    cur ^= 1;
  }

  const int rb = kh * 4, cb = lane & 15;
#pragma unroll
  for (int j = 0; j < 4; ++j) {
    const int col = n0 + wn * 64 + j * 16 + cb;
    const float bv = bias[col];
#pragma unroll
    for (int i = 0; i < 4; ++i) {
#pragma unroll
      for (int r = 0; r < 4; ++r) {
        const size_t row = (size_t)(m0 + wm * 64 + i * 16 + rb + r);
        float v = acc[i][j][r] + bv;
        if (OUT_BF16)
          ((u16*)Cout)[row * N + col] = f2bf(v);
        else
          ((float*)Cout)[row * N + col] = v;
      }
    }
  }
}

// ---------------- RoPE: Pin [M][DIM] bf16 -> Out [B*H][S][HD] bf16 ----------------
__global__ void k_rope(const u16* __restrict__ Pin, const float* __restrict__ cosT,
                       const float* __restrict__ sinT, u16* __restrict__ Out) {
  int idx = blockIdx.x * blockDim.x + threadIdx.x;
  int d4 = idx & 15;
  int h = (idx >> 4) & (NH - 1);
  int s = (idx >> 8) & (SEQ - 1);
  int b = idx >> 19;
  if (b >= BATCH) return;

  const u16* p1 = Pin + (size_t)(b * SEQ + s) * DIMN + h * HDN + d4 * 4;
  ushort4 u1 = *(const ushort4*)p1;
  ushort4 u2 = *(const ushort4*)(p1 + 64);
  float4 c = *(const float4*)(cosT + s * HDN + d4 * 4);
  float4 sn = *(const float4*)(sinT + s * HDN + d4 * 4);

  float a0 = bf2f(u1.x), a1 = bf2f(u1.y), a2 = bf2f(u1.z), a3 = bf2f(u1.w);
  float b0 = bf2f(u2.x), b1 = bf2f(u2.y), b2 = bf2f(u2.z), b3 = bf2f(u2.w);
  ushort4 o1, o2;
  o1.x = f2bf(a0 * c.x - b0 * sn.x);
  o1.y = f2bf(a1 * c.y - b1 * sn.y);
  o1.z = f2bf(a2 * c.z - b2 * sn.z);
  o1.w = f2bf(a3 * c.w - b3 * sn.w);
  o2.x = f2bf(b0 * c.x + a0 * sn.x);
  o2.y = f2bf(b1 * c.y + a1 * sn.y);
  o2.z = f2bf(b2 * c.z + a2 * sn.z);
  o2.w = f2bf(b3 * c.w + a3 * sn.w);

  u16* q = Out + ((size_t)(b * NH + h) * SEQ + s) * HDN + d4 * 4;
  *(ushort4*)q = o1;
  *(ushort4*)(q + 64) = o2;
}

// ---------------- V transpose: Vp [M][DIM] -> Vt [B*H][HD][S] ----------------
__global__ __launch_bounds__(256) void k_transpose_v(const u16* __restrict__ Vp,
                                                     u16* __restrict__ Vt) {
  __shared__ u16 tile[64][72];
  const int bh = blockIdx.z;
  const int b = bh >> 4, h = bh & 15;
  const int s0 = blockIdx.x * 64;
  const int d0 = blockIdx.y * 64;
  const int t = threadIdx.x;
#pragma unroll
  for (int i = 0; i < 4; ++i) {
    int lin = t + i * 256;
    int r = lin >> 4;
    int c = (lin & 15) * 4;
    ushort4 v = *(const ushort4*)(Vp + (size_t)(b * SEQ + s0 + r) * DIMN + h * HDN + d0 + c);
    *(ushort4*)&tile[r][c] = v;
  }
  __syncthreads();
#pragma unroll
  for (int i = 0; i < 4; ++i) {
    int lin = t + i * 256;
    int d = lin >> 4;
    int s4 = (lin & 15) * 4;
    ushort4 o;
    o.x = tile[s4 + 0][d];
    o.y = tile[s4 + 1][d];
    o.z = tile[s4 + 2][d];
    o.w = tile[s4 + 3][d];
    *(ushort4*)(Vt + ((size_t)bh * HDN + d0 + d) * SEQ + s0 + s4) = o;
  }
}

// ---------------- Flash attention (causal), v3 ----------------
// grid: (16 pairs, B*H). Each block processes q-blocks {p, 31-p} (QBLK=64)
// sequentially -> exactly 33 KV-tiles per block (perfect balance).
// 4 waves x 16 q-rows. K/V double-buffered in LDS with prefetch:
// {STAGE next; compute cur; vmcnt(0); s_barrier}.
__global__ __launch_bounds__(256, 2) void k_attn(const u16* __restrict__ Qh,
                                                 const u16* __restrict__ Kh,
                                                 const u16* __restrict__ Vt,
                                                 u16* __restrict__ AO) {
  __shared__ u16 Ks[2][64 * 128];   // swizzled chunks, row=kv (256B)
  __shared__ u16 Vs[2][128 * 64];   // swizzled chunks, row=d (128B)
  __shared__ u16 Ps[4][16][72];     // per-wave P, 144B stride
  const int tid = threadIdx.x, lane = tid & 63, w = tid >> 6;
  const int bh = blockIdx.y;
  const int b = bh >> 4, h = bh & 15;
  const int rb = (lane >> 4) * 4, cb = lane & 15, kh = lane >> 4;
  const int sw = cb & 7;

  // staging address precompute (linear LDS dest <- swizzled global src)
  int rK[4], cK[4], rV[4], cV[4];
#pragma unroll
  for (int i = 0; i < 4; ++i) {
    const int off = w * 4096 + i * 1024 + lane * 16;  // byte offset in 16KB tile
    rK[i] = off >> 8;
    cK[i] = ((off >> 4) & 15) ^ (rK[i] & 7);
    rV[i] = off >> 7;
    cV[i] = ((off >> 4) & 7) ^ (rV[i] & 7);
  }

  const u16* gK = Kh + (size_t)bh * SEQ * HDN;
  const u16* gV = Vt + (size_t)bh * HDN * SEQ;
  const float scale = 0.08838834764831843f;  // 1/sqrt(128)

  auto stage = [&](int buf, int kv0) {
    u16* KsB = &Ks[buf][0] + w * 2048;
    u16* VsB = &Vs[buf][0] + w * 2048;
#pragma unroll
    for (int i = 0; i < 4; ++i) {
      gld16(gK + (size_t)(kv0 + rK[i]) * HDN + cK[i] * 8, KsB + i * 512);
      gld16(gV + (size_t)rV[i] * SEQ + kv0 + cV[i] * 8, VsB + i * 512);
    }
  };

  auto run_segment = [&](int qi) {
    const int q0 = qi * 64;
    const int qw = q0 + w * 16;

    // hoist Q A-fragments: row = qw + cb, k = ks*32 + kh*8
    short8 aq[4];
    {
      const u16* qp = Qh + ((size_t)bh * SEQ + qw + cb) * HDN + kh * 8;
#pragma unroll
      for (int ks = 0; ks < 4; ++ks) aq[ks] = *(const short8*)(qp + ks * 32);
    }

    f32x4 accO[8] = {};
    float m_i[4], l_i[4];
#pragma unroll
    for (int r = 0; r < 4; ++r) {
      m_i[r] = -1e30f;
      l_i[r] = 0.f;
    }

    const int nt = qi + 1;
    stage(0, 0);
    waitbar();
    int cur = 0;

    for (int t = 0; t < nt; ++t) {
      const int kv0 = t * 64;
      if (t + 1 < nt) stage(cur ^ 1, (t + 1) * 64);

      const u16* KsB = &Ks[cur][0];
      const u16* VsB = &Vs[cur][0];

      // S = Q K^T
      f32x4 sc[4] = {};
      __builtin_amdgcn_s_setprio(1);
#pragma unroll
      for (int f = 0; f < 4; ++f)
#pragma unroll
        for (int ks = 0; ks < 4; ++ks) {
          const int krow = f * 16 + cb;
          short8 bk = *(const short8*)(KsB + krow * 128 + (((ks * 4 + kh) ^ sw) * 8));
          sc[f] = __builtin_amdgcn_mfma_f32_16x16x32_bf16(aq[ks], bk, sc[f], 0, 0, 0);
        }
      __builtin_amdgcn_s_setprio(0);

      // scale + causal mask (only last tile is partial)
      if (t == nt - 1) {
#pragma unroll
        for (int f = 0; f < 4; ++f) {
          const int kva = kv0 + f * 16 + cb;
#pragma unroll
          for (int r = 0; r < 4; ++r) {
            float v = sc[f][r] * scale;
            sc[f][r] = (kva <= qw + rb + r) ? v : -1e30f;
          }
        }
      } else {
#pragma unroll
        for (int f = 0; f < 4; ++f)
#pragma unroll
          for (int r = 0; r < 4; ++r) sc[f][r] *= scale;
      }

      // online softmax per row (16-lane group reduce)
      float pm[4], alpha[4];
#pragma unroll
      for (int r = 0; r < 4; ++r) {
        float v = fmaxf(fmaxf(sc[0][r], sc[1][r]), fmaxf(sc[2][r], sc[3][r]));
        v = fmaxf(v, __shfl_xor(v, 1));
        v = fmaxf(v, __shfl_xor(v, 2));
        v = fmaxf(v, __shfl_xor(v, 4));
        v = fmaxf(v, __shfl_xor(v, 8));
        pm[r] = v;
      }
#pragma unroll
      for (int r = 0; r < 4; ++r) {
        float nm = fmaxf(m_i[r], pm[r]);
        alpha[r] = __expf(m_i[r] - nm);
        m_i[r] = nm;
      }
#pragma unroll
      for (int f = 0; f < 4; ++f)
#pragma unroll
        for (int r = 0; r < 4; ++r) sc[f][r] = __expf(sc[f][r] - m_i[r]);
#pragma unroll
      for (int r = 0; r < 4; ++r) {
        float s = sc[0][r] + sc[1][r] + sc[2][r] + sc[3][r];
        s += __shfl_xor(s, 1);
        s += __shfl_xor(s, 2);
        s += __shfl_xor(s, 4);
        s += __shfl_xor(s, 8);
        l_i[r] = l_i[r] * alpha[r] + s;
      }
#pragma unroll
      for (int nf = 0; nf < 8; ++nf)
#pragma unroll
        for (int r = 0; r < 4; ++r) accO[nf][r] *= alpha[r];

      // P -> per-wave padded LDS (intra-wave LDS is in-order; no barrier)
      asm volatile("" ::: "memory");
#pragma unroll
      for (int f = 0; f < 4; ++f)
#pragma unroll
        for (int r = 0; r < 4; ++r) Ps[w][rb + r][f * 16 + cb] = f2bf(sc[f][r]);
      asm volatile("" ::: "memory");

      short8 pa[2];
#pragma unroll
      for (int kk = 0; kk < 2; ++kk)
        pa[kk] = *(const short8*)&Ps[w][cb][kk * 32 + kh * 8];

      // O += P V
      __builtin_amdgcn_s_setprio(1);
#pragma unroll
      for (int nf = 0; nf < 8; ++nf)
#pragma unroll
        for (int kk = 0; kk < 2; ++kk) {
          const int vrow = nf * 16 + cb;
          short8 bv = *(const short8*)(VsB + vrow * 64 + (((kk * 4 + kh) ^ sw) * 8));
          accO[nf] = __builtin_amdgcn_mfma_f32_16x16x32_bf16(pa[kk], bv, accO[nf], 0, 0, 0);
        }
      __builtin_amdgcn_s_setprio(0);

      waitbar();
      cur ^= 1;
    }

    // epilogue
    float inv[4];
#pragma unroll
    for (int r = 0; r < 4; ++r) inv[r] = 1.f / l_i[r];
#pragma unroll
    for (int nf = 0; nf < 8; ++nf)
#pragma unroll
      for (int r = 0; r < 4; ++r) {
        const size_t row = (size_t)(b * SEQ + qw + rb + r);
        AO[row * DIMN + h * HDN + nf * 16 + cb] = f2bf(accO[nf][r] * inv[r]);
      }
  };

  const int p = blockIdx.x;
  run_segment(p);
  run_segment(31 - p);
}

// ---------------- launch ----------------
extern "C" void kernel_launch(void* const* d_in, const int* in_sizes, int n_in,
                              void* d_out, int out_size, void* d_ws, size_t ws_size,
                              hipStream_t stream) {
  const float* query = (const float*)d_in[0];
  const float* key_value = (const float*)d_in[1];
  const float* cosT = (const float*)d_in[2];
  const float* sinT = (const float*)d_in[3];
  const float* wq = (const float*)d_in[4];
  const float* bq = (const float*)d_in[5];
  const float* wk = (const float*)d_in[6];
  const float* bk = (const float*)d_in[7];
  const float* wv = (const float*)d_in[8];
  const float* bv = (const float*)d_in[9];
  const float* wo = (const float*)d_in[10];
  const float* bo = (const float*)d_in[11];
  float* out = (float*)d_out;

  const size_t WB = (size_t)DIMN * DIMN * 2;
  const size_t XB = (size_t)MROWS * DIMN * 2;
  char* ws = (char*)d_ws;
  size_t off = 0;
  auto alloc = [&](size_t bytes) {
    char* p = ws + off;
    off += bytes;
    return p;
  };
  u16* wq_bf = (u16*)alloc(WB);
  u16* wk_bf = (u16*)alloc(WB);
  u16* wv_bf = (u16*)alloc(WB);
  u16* wo_bf = (u16*)alloc(WB);
  u16* xq_bf = (u16*)alloc(XB);
  u16* xkv_bf = (u16*)alloc(XB);
  u16* Qp = (u16*)alloc(XB);
  u16* Kp = (u16*)alloc(XB);
  u16* Vp = (u16*)alloc(XB);
  u16* Qh = (u16*)alloc(XB);
  u16* Kh = (u16*)alloc(XB);
  u16* Vt = (u16*)alloc(XB);
  u16* AO = (u16*)alloc(XB);

  auto conv = [&](const float* s, u16* d, int n) {
    k_f32_to_bf16<<<dim3(n / 4 / 256), dim3(256), 0, stream>>>(s, d, n);
  };
  conv(wq, wq_bf, DIMN * DIMN);
  conv(wk, wk_bf, DIMN * DIMN);
  conv(wv, wv_bf, DIMN * DIMN);
  conv(wo, wo_bf, DIMN * DIMN);
  conv(query, xq_bf, MROWS * DIMN);
  conv(key_value, xkv_bf, MROWS * DIMN);

  dim3 gg(DIMN / 128, MROWS / 128);
  k_gemm_bt<1><<<gg, 256, 0, stream>>>(xq_bf, wq_bf, bq, Qp, MROWS, DIMN, DIMN);
  k_gemm_bt<1><<<gg, 256, 0, stream>>>(xkv_bf, wk_bf, bk, Kp, MROWS, DIMN, DIMN);
  k_gemm_bt<1><<<gg, 256, 0, stream>>>(xkv_bf, wv_bf, bv, Vp, MROWS, DIMN, DIMN);

  const int ropeN = BATCH * SEQ * NH * 16;
  k_rope<<<dim3(ropeN / 256), dim3(256), 0, stream>>>(Qp, cosT, sinT, Qh);
  k_rope<<<dim3(ropeN / 256), dim3(256), 0, stream>>>(Kp, cosT, sinT, Kh);
  k_transpose_v<<<dim3(SEQ / 64, 2, BATCH * NH), dim3(256), 0, stream>>>(Vp, Vt);

  k_attn<<<dim3(16, BATCH * NH), 256, 0, stream>>>(Qh, Kh, Vt, AO);

  k_gemm_bt<0><<<gg, 256, 0, stream>>>(AO, wo_bf, bo, out, MROWS, DIMN, DIMN);
}